// Round 1
// baseline (515.671 us; speedup 1.0000x reference)
//
#include <hip/hip_runtime.h>
#include <math.h>

// Fused: per-position dual C=64 -> 1 projections + LeakyReLU(0.3) + sigmoid gate.
// Memory-bound: 512 MiB read / 4 MiB write -> ~82 us floor at 6.3 TB/s.
//
// Layout trick: 16 lanes per position, 1 float4 (4 channels) per lane.
// Lane i of a wave reads bytes [base + 16*i, base+16*i+16) -> fully
// coalesced 1 KiB per wave load instruction.

#define NEG_SLOPE 0.3f
#define C_DIM 64

__global__ __launch_bounds__(256) void attn_gate_kernel(
    const float* __restrict__ xatt,
    const float* __restrict__ xsaut,
    const float* __restrict__ W_act,   // [64]
    const float* __restrict__ b_act,   // [1]
    const float* __restrict__ W_saut,  // [64]
    const float* __restrict__ b_saut,  // [1]
    const float* __restrict__ W2,      // [1]
    const float* __restrict__ b2,      // [1]
    float* __restrict__ out,
    int npos)                          // B*L
{
    const int lane16  = threadIdx.x & 15;                      // channel-group id (4 ch each)
    const int group   = (blockIdx.x * blockDim.x + threadIdx.x) >> 4;  // position index
    const int ngroups = (gridDim.x * blockDim.x) >> 4;

    // Per-lane weight fragments (4 channels each). Broadcast through L1/L2; tiny.
    const float4 wa = ((const float4*)W_act)[lane16];
    const float4 ws = ((const float4*)W_saut)[lane16];
    const float  ba = b_act[0];
    const float  bs = b_saut[0];
    const float  w2 = W2[0];
    const float  c2 = b2[0];

    const float4* __restrict__ a4 = (const float4*)xatt;
    const float4* __restrict__ s4 = (const float4*)xsaut;

    for (int pos = group; pos < npos; pos += ngroups) {
        const long base = (long)pos * (C_DIM / 4) + lane16;
        const float4 a = a4[base];
        const float4 s = s4[base];

        float pa = a.x * wa.x + a.y * wa.y + a.z * wa.z + a.w * wa.w;
        float ps = s.x * ws.x + s.y * ws.y + s.z * ws.z + s.w * ws.w;

        // Butterfly reduce both partials across the 16 lanes of this group.
        #pragma unroll
        for (int off = 8; off > 0; off >>= 1) {
            pa += __shfl_xor(pa, off, 16);
            ps += __shfl_xor(ps, off, 16);
        }

        if (lane16 == 0) {
            const float xa = pa + ba;
            const float xs = ps + bs;
            float h = xa + xs;
            h = (h >= 0.0f) ? h : NEG_SLOPE * h;
            const float z = h * w2 + c2;
            const float g = 1.0f / (1.0f + __expf(-z));
            out[pos] = g * xs;
        }
    }
}

extern "C" void kernel_launch(void* const* d_in, const int* in_sizes, int n_in,
                              void* d_out, int out_size, void* d_ws, size_t ws_size,
                              hipStream_t stream) {
    const float* xatt   = (const float*)d_in[0];
    const float* xsaut  = (const float*)d_in[1];
    const float* W_act  = (const float*)d_in[2];
    const float* b_act  = (const float*)d_in[3];
    const float* W_saut = (const float*)d_in[4];
    const float* b_saut = (const float*)d_in[5];
    const float* W2     = (const float*)d_in[6];
    const float* b2     = (const float*)d_in[7];
    float* out = (float*)d_out;

    const int npos = out_size;  // B*L positions, one output each

    // 4096 blocks x 256 threads = 65536 groups; each group strides ~16 positions.
    // 16 waves-worth of blocks per CU keeps the memory pipe saturated.
    const int blocks = 4096;
    attn_gate_kernel<<<blocks, 256, 0, stream>>>(
        xatt, xsaut, W_act, b_act, W_saut, b_saut, W2, b2, out, npos);
}